// Round 1
// baseline (3750.089 us; speedup 1.0000x reference)
//
#include <hip/hip_runtime.h>

// GCNII on MI355X, all fp32.
// Pipeline per call:
//   1. CSR build by dst (hist -> scan -> scatter), once per call
//   2. Wc[i] = theta_i*conv_w[i] + (1-theta_i)*I   (absorbs identity-mapping mix)
//   3. h0 = x@W_in + b_in
//   4. 8x fused layer: per 32-row block: CSR gather-accum (regs) -> support =
//      0.9*acc + 0.1*h0 -> LDS -> @Wc (LDS) -> relu -> store
//   5. out = h@W_out + b_out

constexpr int NN = 100000;
constexpr int EE = 3200000;

// ---------------- CSR build ----------------
__global__ void hist_kernel(const int* __restrict__ dst, int* __restrict__ cnt, int e) {
    int i = blockIdx.x * 256 + threadIdx.x;
    if (i < e) atomicAdd(&cnt[dst[i]], 1);
}

__global__ __launch_bounds__(1024) void scan_kernel(const int* __restrict__ cnt,
                                                    int* __restrict__ row_ptr,
                                                    int* __restrict__ cursor, int n) {
    __shared__ int wsum[16];
    __shared__ int s_carry;
    const int lane = threadIdx.x & 63, wid = threadIdx.x >> 6;
    if (threadIdx.x == 0) s_carry = 0;
    __syncthreads();
    for (int base = 0; base < n; base += 1024) {
        int i = base + threadIdx.x;
        int v = (i < n) ? cnt[i] : 0;
        int x = v;
        #pragma unroll
        for (int d = 1; d < 64; d <<= 1) {
            int y = __shfl_up(x, (unsigned)d);
            if (lane >= d) x += y;
        }
        if (lane == 63) wsum[wid] = x;
        __syncthreads();
        int woff = 0;
        for (int w = 0; w < wid; ++w) woff += wsum[w];
        int carry = s_carry;
        if (i < n) {
            int excl = carry + woff + x - v;
            row_ptr[i] = excl;
            cursor[i] = excl;
        }
        __syncthreads();
        if (threadIdx.x == 1023) s_carry = carry + woff + x;
        __syncthreads();
    }
    if (threadIdx.x == 0) row_ptr[n] = s_carry;
}

__global__ void scatter_kernel(const int* __restrict__ src, const int* __restrict__ dst,
                               const float* __restrict__ val, int* __restrict__ cursor,
                               int2* __restrict__ csr, int e) {
    int i = blockIdx.x * 256 + threadIdx.x;
    if (i < e) {
        int p = atomicAdd(&cursor[dst[i]], 1);
        csr[p] = make_int2(src[i], __float_as_int(val[i]));
    }
}

// ---------------- Wc = theta*W + (1-theta)*I ----------------
__global__ void prep_wc_kernel(const float* __restrict__ conv_w, float* __restrict__ Wc) {
    int layer = blockIdx.y;
    int idx = blockIdx.x * 256 + threadIdx.x;          // 0..16383
    float theta = logf(0.5f / (float)(layer + 1) + 1.0f);
    int k = idx >> 7, j = idx & 127;
    float w = conv_w[layer * 16384 + idx];
    Wc[layer * 16384 + idx] = theta * w + ((k == j) ? (1.0f - theta) : 0.0f);
}

// ---------------- fc_in: h0 = x@W_in + b_in ----------------
__global__ __launch_bounds__(256, 2) void fc_in_kernel(const float* __restrict__ x,
                                                       const float* __restrict__ W,
                                                       const float* __restrict__ b,
                                                       float* __restrict__ h0) {
    __shared__ float sW[128 * 128];   // 64KB
    __shared__ float sA[32 * 128];    // 16KB
    const int tid = threadIdx.x;
    #pragma unroll
    for (int t = 0; t < 16; ++t)
        ((float4*)sW)[t * 256 + tid] = ((const float4*)W)[t * 256 + tid];
    const float4* xs = (const float4*)(x + (size_t)blockIdx.x * 32 * 128);
    #pragma unroll
    for (int t = 0; t < 4; ++t)
        ((float4*)sA)[t * 256 + tid] = xs[t * 256 + tid];
    __syncthreads();

    const int rowg = tid >> 5, colg = tid & 31;
    float4 bias = ((const float4*)b)[colg];
    float acc[4][4];
    #pragma unroll
    for (int r = 0; r < 4; ++r) { acc[r][0] = bias.x; acc[r][1] = bias.y; acc[r][2] = bias.z; acc[r][3] = bias.w; }

    for (int k = 0; k < 128; ++k) {
        float4 w = *(const float4*)&sW[k * 128 + (colg << 2)];
        float s[4];
        #pragma unroll
        for (int r = 0; r < 4; ++r) s[r] = sA[((rowg << 2) + r) * 128 + k];
        #pragma unroll
        for (int r = 0; r < 4; ++r) {
            acc[r][0] = fmaf(s[r], w.x, acc[r][0]);
            acc[r][1] = fmaf(s[r], w.y, acc[r][1]);
            acc[r][2] = fmaf(s[r], w.z, acc[r][2]);
            acc[r][3] = fmaf(s[r], w.w, acc[r][3]);
        }
    }
    float* outp = h0 + (size_t)blockIdx.x * 32 * 128;
    #pragma unroll
    for (int r = 0; r < 4; ++r) {
        float4 o = make_float4(acc[r][0], acc[r][1], acc[r][2], acc[r][3]);
        *(float4*)(outp + ((rowg << 2) + r) * 128 + (colg << 2)) = o;
    }
}

// ---------------- fused layer ----------------
__global__ __launch_bounds__(256, 2) void layer_kernel(const float* __restrict__ h,
                                                       const float* __restrict__ h0,
                                                       const int2* __restrict__ csr,
                                                       const int* __restrict__ row_ptr,
                                                       const float* __restrict__ Wc,
                                                       float* __restrict__ hn) {
    __shared__ float sW[128 * 128];   // 64KB
    __shared__ float sS[32 * 128];    // 16KB
    const int tid = threadIdx.x;
    #pragma unroll
    for (int t = 0; t < 16; ++t)
        ((float4*)sW)[t * 256 + tid] = ((const float4*)Wc)[t * 256 + tid];

    const int wid = tid >> 6, lane = tid & 63;
    const int fo = lane << 1;                       // feature pair offset
    const int row0 = blockIdx.x * 32;

    // Phase A: gather-accumulate 8 rows per wave
    for (int rr = 0; rr < 8; ++rr) {
        const int r = row0 + wid * 8 + rr;
        const int e0 = row_ptr[r], e1 = row_ptr[r + 1];
        float a0 = 0.f, a1 = 0.f;
        int e = e0;
        for (; e + 4 <= e1; e += 4) {
            int2 p0 = csr[e], p1 = csr[e + 1], p2 = csr[e + 2], p3 = csr[e + 3];
            float2 g0 = *(const float2*)(h + (p0.x << 7) + fo);
            float2 g1 = *(const float2*)(h + (p1.x << 7) + fo);
            float2 g2 = *(const float2*)(h + (p2.x << 7) + fo);
            float2 g3 = *(const float2*)(h + (p3.x << 7) + fo);
            float v0 = __int_as_float(p0.y), v1 = __int_as_float(p1.y);
            float v2 = __int_as_float(p2.y), v3 = __int_as_float(p3.y);
            a0 = fmaf(v0, g0.x, a0); a1 = fmaf(v0, g0.y, a1);
            a0 = fmaf(v1, g1.x, a0); a1 = fmaf(v1, g1.y, a1);
            a0 = fmaf(v2, g2.x, a0); a1 = fmaf(v2, g2.y, a1);
            a0 = fmaf(v3, g3.x, a0); a1 = fmaf(v3, g3.y, a1);
        }
        for (; e < e1; ++e) {
            int2 p = csr[e];
            float2 g = *(const float2*)(h + (p.x << 7) + fo);
            float v = __int_as_float(p.y);
            a0 = fmaf(v, g.x, a0); a1 = fmaf(v, g.y, a1);
        }
        float2 h0v = *(const float2*)(h0 + ((size_t)r << 7) + fo);
        float2 sv;
        sv.x = 0.9f * a0 + 0.1f * h0v.x;
        sv.y = 0.9f * a1 + 0.1f * h0v.y;
        *(float2*)&sS[(wid * 8 + rr) * 128 + fo] = sv;
    }
    __syncthreads();

    // Phase B: out = S @ Wc, relu, store
    const int rowg = tid >> 5, colg = tid & 31;
    float acc[4][4] = {};
    for (int k = 0; k < 128; ++k) {
        float4 w = *(const float4*)&sW[k * 128 + (colg << 2)];
        float s[4];
        #pragma unroll
        for (int r = 0; r < 4; ++r) s[r] = sS[((rowg << 2) + r) * 128 + k];
        #pragma unroll
        for (int r = 0; r < 4; ++r) {
            acc[r][0] = fmaf(s[r], w.x, acc[r][0]);
            acc[r][1] = fmaf(s[r], w.y, acc[r][1]);
            acc[r][2] = fmaf(s[r], w.z, acc[r][2]);
            acc[r][3] = fmaf(s[r], w.w, acc[r][3]);
        }
    }
    float* outp = hn + (size_t)row0 * 128;
    #pragma unroll
    for (int r = 0; r < 4; ++r) {
        float4 o;
        o.x = fmaxf(acc[r][0], 0.f);
        o.y = fmaxf(acc[r][1], 0.f);
        o.z = fmaxf(acc[r][2], 0.f);
        o.w = fmaxf(acc[r][3], 0.f);
        *(float4*)(outp + ((rowg << 2) + r) * 128 + (colg << 2)) = o;
    }
}

// ---------------- fc_out: out = h@W_out + b_out ----------------
__global__ __launch_bounds__(256, 3) void fc_out_kernel(const float* __restrict__ h,
                                                        const float* __restrict__ W,
                                                        const float* __restrict__ b,
                                                        float* __restrict__ out, int n) {
    __shared__ float sW[128 * 40];    // 20KB
    __shared__ float sA[64 * 128];    // 32KB
    const int tid = threadIdx.x;
    #pragma unroll
    for (int t = 0; t < 5; ++t)
        ((float4*)sW)[t * 256 + tid] = ((const float4*)W)[t * 256 + tid];
    const int row0 = blockIdx.x * 64;
    #pragma unroll
    for (int t = 0; t < 8; ++t) {
        int idx = t * 256 + tid;              // float4 index, 2048 total
        int row = idx >> 5;
        int gr = row0 + row;
        float4 v = make_float4(0.f, 0.f, 0.f, 0.f);
        if (gr < n) v = ((const float4*)h)[(size_t)gr * 32 + (idx & 31)];
        ((float4*)sA)[idx] = v;
    }
    __syncthreads();

    const int rowg = tid >> 3;   // 32 groups x 2 rows
    const int colg = tid & 7;    // 8 groups x 5 cols
    float acc[2][5];
    #pragma unroll
    for (int c = 0; c < 5; ++c) {
        float bb = b[colg * 5 + c];
        acc[0][c] = bb; acc[1][c] = bb;
    }
    for (int k = 0; k < 128; ++k) {
        float s0 = sA[(rowg * 2 + 0) * 128 + k];
        float s1 = sA[(rowg * 2 + 1) * 128 + k];
        #pragma unroll
        for (int c = 0; c < 5; ++c) {
            float w = sW[k * 40 + colg * 5 + c];
            acc[0][c] = fmaf(s0, w, acc[0][c]);
            acc[1][c] = fmaf(s1, w, acc[1][c]);
        }
    }
    #pragma unroll
    for (int rr = 0; rr < 2; ++rr) {
        int r = row0 + rowg * 2 + rr;
        if (r < n) {
            #pragma unroll
            for (int c = 0; c < 5; ++c)
                out[(size_t)r * 40 + colg * 5 + c] = acc[rr][c];
        }
    }
}

extern "C" void kernel_launch(void* const* d_in, const int* in_sizes, int n_in,
                              void* d_out, int out_size, void* d_ws, size_t ws_size,
                              hipStream_t stream) {
    const float* x      = (const float*)d_in[0];
    const int*   esrc   = (const int*)d_in[1];
    const int*   edst   = (const int*)d_in[2];
    const float* eval   = (const float*)d_in[3];
    const float* W_in   = (const float*)d_in[4];
    const float* b_in   = (const float*)d_in[5];
    const float* conv_w = (const float*)d_in[6];
    const float* W_out  = (const float*)d_in[7];
    const float* b_out  = (const float*)d_in[8];
    float* out = (float*)d_out;

    // workspace carve-up (~181 MB total)
    float* h0      = (float*)d_ws;
    float* hA      = h0 + (size_t)NN * 128;
    float* hB      = hA + (size_t)NN * 128;
    float* Wc      = hB + (size_t)NN * 128;
    int*   row_ptr = (int*)(Wc + 8 * 128 * 128);
    int*   cursor  = row_ptr + (NN + 2);      // padded for 8B alignment of csr
    int*   cnt     = cursor + NN;
    int2*  csr     = (int2*)(cnt + NN);

    // --- CSR build ---
    hipMemsetAsync(cnt, 0, NN * sizeof(int), stream);
    hist_kernel<<<EE / 256, 256, 0, stream>>>(edst, cnt, EE);
    scan_kernel<<<1, 1024, 0, stream>>>(cnt, row_ptr, cursor, NN);
    scatter_kernel<<<EE / 256, 256, 0, stream>>>(esrc, edst, eval, cursor, csr, EE);

    // --- weights prep ---
    prep_wc_kernel<<<dim3(64, 8), 256, 0, stream>>>(conv_w, Wc);

    // --- fc_in ---
    fc_in_kernel<<<NN / 32, 256, 0, stream>>>(x, W_in, b_in, h0);

    // --- 8 fused layers, ping-pong hA/hB ---
    const float* hin = h0;
    float* hout = hA;
    for (int i = 0; i < 8; ++i) {
        layer_kernel<<<NN / 32, 256, 0, stream>>>(hin, h0, csr, row_ptr, Wc + i * 16384, hout);
        hin = hout;
        hout = (hout == hA) ? hB : hA;
    }

    // --- fc_out ---
    fc_out_kernel<<<(NN + 63) / 64, 256, 0, stream>>>(hin, W_out, b_out, out, NN);
}

// Round 2
// 2601.869 us; speedup vs baseline: 1.4413x; 1.4413x over previous
//
#include <hip/hip_runtime.h>

// GCNII on MI355X, all fp32.
//   1. CSR build by dst (hist -> scan -> scatter), once per call
//   2. Wc[i] = theta_i*conv_w[i] + (1-theta_i)*I   (absorbs identity-mapping mix)
//   3. h0 = x@W_in + b_in
//   4. 8x fused layer: per 32-row block: CSR gather-accum (2 edges/wave, float4/lane)
//      -> support = 0.9*acc + 0.1*h0 -> LDS -> @Wc (Wc from global, L2-hot) -> relu
//   5. out = h@W_out + b_out
// R1 change: removed 64KB LDS weight stage (occupancy 8->16 waves/CU) and doubled
// per-wave gather MLP (2 edges x float4/lane, 8 rows in flight).

constexpr int NN = 100000;
constexpr int EE = 3200000;

// ---------------- CSR build ----------------
__global__ void hist_kernel(const int* __restrict__ dst, int* __restrict__ cnt, int e) {
    int i = blockIdx.x * 256 + threadIdx.x;
    if (i < e) atomicAdd(&cnt[dst[i]], 1);
}

__global__ __launch_bounds__(1024) void scan_kernel(const int* __restrict__ cnt,
                                                    int* __restrict__ row_ptr,
                                                    int* __restrict__ cursor, int n) {
    __shared__ int wsum[16];
    __shared__ int s_carry;
    const int lane = threadIdx.x & 63, wid = threadIdx.x >> 6;
    if (threadIdx.x == 0) s_carry = 0;
    __syncthreads();
    for (int base = 0; base < n; base += 1024) {
        int i = base + threadIdx.x;
        int v = (i < n) ? cnt[i] : 0;
        int x = v;
        #pragma unroll
        for (int d = 1; d < 64; d <<= 1) {
            int y = __shfl_up(x, (unsigned)d);
            if (lane >= d) x += y;
        }
        if (lane == 63) wsum[wid] = x;
        __syncthreads();
        int woff = 0;
        for (int w = 0; w < wid; ++w) woff += wsum[w];
        int carry = s_carry;
        if (i < n) {
            int excl = carry + woff + x - v;
            row_ptr[i] = excl;
            cursor[i] = excl;
        }
        __syncthreads();
        if (threadIdx.x == 1023) s_carry = carry + woff + x;
        __syncthreads();
    }
    if (threadIdx.x == 0) row_ptr[n] = s_carry;
}

__global__ void scatter_kernel(const int* __restrict__ src, const int* __restrict__ dst,
                               const float* __restrict__ val, int* __restrict__ cursor,
                               int2* __restrict__ csr, int e) {
    int i = blockIdx.x * 256 + threadIdx.x;
    if (i < e) {
        int p = atomicAdd(&cursor[dst[i]], 1);
        csr[p] = make_int2(src[i], __float_as_int(val[i]));
    }
}

// ---------------- Wc = theta*W + (1-theta)*I ----------------
__global__ void prep_wc_kernel(const float* __restrict__ conv_w, float* __restrict__ Wc) {
    int layer = blockIdx.y;
    int idx = blockIdx.x * 256 + threadIdx.x;          // 0..16383
    float theta = logf(0.5f / (float)(layer + 1) + 1.0f);
    int k = idx >> 7, j = idx & 127;
    float w = conv_w[layer * 16384 + idx];
    Wc[layer * 16384 + idx] = theta * w + ((k == j) ? (1.0f - theta) : 0.0f);
}

// ---------------- fc_in: h0 = x@W_in + b_in ----------------
__global__ __launch_bounds__(256, 2) void fc_in_kernel(const float* __restrict__ x,
                                                       const float* __restrict__ W,
                                                       const float* __restrict__ b,
                                                       float* __restrict__ h0) {
    __shared__ float sW[128 * 128];   // 64KB
    __shared__ float sA[32 * 128];    // 16KB
    const int tid = threadIdx.x;
    #pragma unroll
    for (int t = 0; t < 16; ++t)
        ((float4*)sW)[t * 256 + tid] = ((const float4*)W)[t * 256 + tid];
    const float4* xs = (const float4*)(x + (size_t)blockIdx.x * 32 * 128);
    #pragma unroll
    for (int t = 0; t < 4; ++t)
        ((float4*)sA)[t * 256 + tid] = xs[t * 256 + tid];
    __syncthreads();

    const int rowg = tid >> 5, colg = tid & 31;
    float4 bias = ((const float4*)b)[colg];
    float acc[4][4];
    #pragma unroll
    for (int r = 0; r < 4; ++r) { acc[r][0] = bias.x; acc[r][1] = bias.y; acc[r][2] = bias.z; acc[r][3] = bias.w; }

    for (int k = 0; k < 128; ++k) {
        float4 w = *(const float4*)&sW[k * 128 + (colg << 2)];
        float s[4];
        #pragma unroll
        for (int r = 0; r < 4; ++r) s[r] = sA[((rowg << 2) + r) * 128 + k];
        #pragma unroll
        for (int r = 0; r < 4; ++r) {
            acc[r][0] = fmaf(s[r], w.x, acc[r][0]);
            acc[r][1] = fmaf(s[r], w.y, acc[r][1]);
            acc[r][2] = fmaf(s[r], w.z, acc[r][2]);
            acc[r][3] = fmaf(s[r], w.w, acc[r][3]);
        }
    }
    float* outp = h0 + (size_t)blockIdx.x * 32 * 128;
    #pragma unroll
    for (int r = 0; r < 4; ++r) {
        float4 o = make_float4(acc[r][0], acc[r][1], acc[r][2], acc[r][3]);
        *(float4*)(outp + ((rowg << 2) + r) * 128 + (colg << 2)) = o;
    }
}

// ---------------- fused layer ----------------
// Phase A: wave owns 8 rows; 2 edges in flight across half-waves, float4/lane,
//          unroll 4 -> 8 row-gathers outstanding. Cross-half reduce via shfl_xor(32).
// Phase B: S (LDS, 16KB) @ Wc (global, L2-hot) -> relu -> store.
__global__ __launch_bounds__(256, 4) void layer_kernel(const float* __restrict__ h,
                                                       const float* __restrict__ h0,
                                                       const int2* __restrict__ csr,
                                                       const int* __restrict__ row_ptr,
                                                       const float* __restrict__ Wc,
                                                       float* __restrict__ hn) {
    __shared__ float sS[32 * 128];    // 16KB
    const int tid = threadIdx.x;
    const int wid = tid >> 6, lane = tid & 63;
    const int half = lane >> 5;             // which of 2 concurrent edges
    const int fq = lane & 31;               // float4 slot within the 128-wide row
    const int row0 = blockIdx.x * 32;

    for (int rr = 0; rr < 8; ++rr) {
        const int r = row0 + wid * 8 + rr;
        const int e0 = row_ptr[r], e1 = row_ptr[r + 1];
        float4 acc = make_float4(0.f, 0.f, 0.f, 0.f);
        int e = e0;
        for (; e + 8 <= e1; e += 8) {
            int2 p0 = csr[e + half];
            int2 p1 = csr[e + 2 + half];
            int2 p2 = csr[e + 4 + half];
            int2 p3 = csr[e + 6 + half];
            float4 g0 = *(const float4*)(h + ((size_t)p0.x << 7) + (fq << 2));
            float4 g1 = *(const float4*)(h + ((size_t)p1.x << 7) + (fq << 2));
            float4 g2 = *(const float4*)(h + ((size_t)p2.x << 7) + (fq << 2));
            float4 g3 = *(const float4*)(h + ((size_t)p3.x << 7) + (fq << 2));
            float v0 = __int_as_float(p0.y), v1 = __int_as_float(p1.y);
            float v2 = __int_as_float(p2.y), v3 = __int_as_float(p3.y);
            acc.x = fmaf(v0, g0.x, acc.x); acc.y = fmaf(v0, g0.y, acc.y);
            acc.z = fmaf(v0, g0.z, acc.z); acc.w = fmaf(v0, g0.w, acc.w);
            acc.x = fmaf(v1, g1.x, acc.x); acc.y = fmaf(v1, g1.y, acc.y);
            acc.z = fmaf(v1, g1.z, acc.z); acc.w = fmaf(v1, g1.w, acc.w);
            acc.x = fmaf(v2, g2.x, acc.x); acc.y = fmaf(v2, g2.y, acc.y);
            acc.z = fmaf(v2, g2.z, acc.z); acc.w = fmaf(v2, g2.w, acc.w);
            acc.x = fmaf(v3, g3.x, acc.x); acc.y = fmaf(v3, g3.y, acc.y);
            acc.z = fmaf(v3, g3.z, acc.z); acc.w = fmaf(v3, g3.w, acc.w);
        }
        for (; e < e1; e += 2) {
            int idx = e + half;
            int2 p = csr[(idx < e1) ? idx : (e1 - 1)];
            float v = (idx < e1) ? __int_as_float(p.y) : 0.f;
            float4 g = *(const float4*)(h + ((size_t)p.x << 7) + (fq << 2));
            acc.x = fmaf(v, g.x, acc.x); acc.y = fmaf(v, g.y, acc.y);
            acc.z = fmaf(v, g.z, acc.z); acc.w = fmaf(v, g.w, acc.w);
        }
        // combine the two half-wave partial sums
        acc.x += __shfl_xor(acc.x, 32);
        acc.y += __shfl_xor(acc.y, 32);
        acc.z += __shfl_xor(acc.z, 32);
        acc.w += __shfl_xor(acc.w, 32);
        if (half == 0) {
            float4 h0v = *(const float4*)(h0 + ((size_t)r << 7) + (fq << 2));
            float4 sv;
            sv.x = 0.9f * acc.x + 0.1f * h0v.x;
            sv.y = 0.9f * acc.y + 0.1f * h0v.y;
            sv.z = 0.9f * acc.z + 0.1f * h0v.z;
            sv.w = 0.9f * acc.w + 0.1f * h0v.w;
            *(float4*)&sS[(wid * 8 + rr) * 128 + (fq << 2)] = sv;
        }
    }
    __syncthreads();

    // Phase B: out = S @ Wc, relu, store. Wc read from global (64KB, L1/L2-hot).
    const int rowg = tid >> 5, colg = tid & 31;
    const float* wp = Wc + (colg << 2);
    float acc2[4][4] = {};
    for (int k = 0; k < 128; k += 2) {
        float4 w0 = *(const float4*)(wp + ((size_t)k << 7));
        float4 w1 = *(const float4*)(wp + ((size_t)(k + 1) << 7));
        float s0[4], s1[4];
        #pragma unroll
        for (int r = 0; r < 4; ++r) {
            s0[r] = sS[((rowg << 2) + r) * 128 + k];
            s1[r] = sS[((rowg << 2) + r) * 128 + k + 1];
        }
        #pragma unroll
        for (int r = 0; r < 4; ++r) {
            acc2[r][0] = fmaf(s0[r], w0.x, acc2[r][0]);
            acc2[r][1] = fmaf(s0[r], w0.y, acc2[r][1]);
            acc2[r][2] = fmaf(s0[r], w0.z, acc2[r][2]);
            acc2[r][3] = fmaf(s0[r], w0.w, acc2[r][3]);
            acc2[r][0] = fmaf(s1[r], w1.x, acc2[r][0]);
            acc2[r][1] = fmaf(s1[r], w1.y, acc2[r][1]);
            acc2[r][2] = fmaf(s1[r], w1.z, acc2[r][2]);
            acc2[r][3] = fmaf(s1[r], w1.w, acc2[r][3]);
        }
    }
    float* outp = hn + (size_t)row0 * 128;
    #pragma unroll
    for (int r = 0; r < 4; ++r) {
        float4 o;
        o.x = fmaxf(acc2[r][0], 0.f);
        o.y = fmaxf(acc2[r][1], 0.f);
        o.z = fmaxf(acc2[r][2], 0.f);
        o.w = fmaxf(acc2[r][3], 0.f);
        *(float4*)(outp + ((rowg << 2) + r) * 128 + (colg << 2)) = o;
    }
}

// ---------------- fc_out: out = h@W_out + b_out ----------------
__global__ __launch_bounds__(256, 3) void fc_out_kernel(const float* __restrict__ h,
                                                        const float* __restrict__ W,
                                                        const float* __restrict__ b,
                                                        float* __restrict__ out, int n) {
    __shared__ float sW[128 * 40];    // 20KB
    __shared__ float sA[64 * 128];    // 32KB
    const int tid = threadIdx.x;
    #pragma unroll
    for (int t = 0; t < 5; ++t)
        ((float4*)sW)[t * 256 + tid] = ((const float4*)W)[t * 256 + tid];
    const int row0 = blockIdx.x * 64;
    #pragma unroll
    for (int t = 0; t < 8; ++t) {
        int idx = t * 256 + tid;              // float4 index, 2048 total
        int row = idx >> 5;
        int gr = row0 + row;
        float4 v = make_float4(0.f, 0.f, 0.f, 0.f);
        if (gr < n) v = ((const float4*)h)[(size_t)gr * 32 + (idx & 31)];
        ((float4*)sA)[idx] = v;
    }
    __syncthreads();

    const int rowg = tid >> 3;   // 32 groups x 2 rows
    const int colg = tid & 7;    // 8 groups x 5 cols
    float acc[2][5];
    #pragma unroll
    for (int c = 0; c < 5; ++c) {
        float bb = b[colg * 5 + c];
        acc[0][c] = bb; acc[1][c] = bb;
    }
    for (int k = 0; k < 128; ++k) {
        float s0 = sA[(rowg * 2 + 0) * 128 + k];
        float s1 = sA[(rowg * 2 + 1) * 128 + k];
        #pragma unroll
        for (int c = 0; c < 5; ++c) {
            float w = sW[k * 40 + colg * 5 + c];
            acc[0][c] = fmaf(s0, w, acc[0][c]);
            acc[1][c] = fmaf(s1, w, acc[1][c]);
        }
    }
    #pragma unroll
    for (int rr = 0; rr < 2; ++rr) {
        int r = row0 + rowg * 2 + rr;
        if (r < n) {
            #pragma unroll
            for (int c = 0; c < 5; ++c)
                out[(size_t)r * 40 + colg * 5 + c] = acc[rr][c];
        }
    }
}

extern "C" void kernel_launch(void* const* d_in, const int* in_sizes, int n_in,
                              void* d_out, int out_size, void* d_ws, size_t ws_size,
                              hipStream_t stream) {
    const float* x      = (const float*)d_in[0];
    const int*   esrc   = (const int*)d_in[1];
    const int*   edst   = (const int*)d_in[2];
    const float* eval   = (const float*)d_in[3];
    const float* W_in   = (const float*)d_in[4];
    const float* b_in   = (const float*)d_in[5];
    const float* conv_w = (const float*)d_in[6];
    const float* W_out  = (const float*)d_in[7];
    const float* b_out  = (const float*)d_in[8];
    float* out = (float*)d_out;

    // workspace carve-up (~181 MB total)
    float* h0      = (float*)d_ws;
    float* hA      = h0 + (size_t)NN * 128;
    float* hB      = hA + (size_t)NN * 128;
    float* Wc      = hB + (size_t)NN * 128;
    int*   row_ptr = (int*)(Wc + 8 * 128 * 128);
    int*   cursor  = row_ptr + (NN + 2);      // padded for 8B alignment of csr
    int*   cnt     = cursor + NN;
    int2*  csr     = (int2*)(cnt + NN);

    // --- CSR build ---
    hipMemsetAsync(cnt, 0, NN * sizeof(int), stream);
    hist_kernel<<<EE / 256, 256, 0, stream>>>(edst, cnt, EE);
    scan_kernel<<<1, 1024, 0, stream>>>(cnt, row_ptr, cursor, NN);
    scatter_kernel<<<EE / 256, 256, 0, stream>>>(esrc, edst, eval, cursor, csr, EE);

    // --- weights prep ---
    prep_wc_kernel<<<dim3(64, 8), 256, 0, stream>>>(conv_w, Wc);

    // --- fc_in ---
    fc_in_kernel<<<NN / 32, 256, 0, stream>>>(x, W_in, b_in, h0);

    // --- 8 fused layers, ping-pong hA/hB ---
    const float* hin = h0;
    float* hout = hA;
    for (int i = 0; i < 8; ++i) {
        layer_kernel<<<NN / 32, 256, 0, stream>>>(hin, h0, csr, row_ptr, Wc + i * 16384, hout);
        hin = hout;
        hout = (hout == hA) ? hB : hA;
    }

    // --- fc_out ---
    fc_out_kernel<<<(NN + 63) / 64, 256, 0, stream>>>(hin, W_out, b_out, out, NN);
}